// Round 2
// baseline (2593.491 us; speedup 1.0000x reference)
//
#include <hip/hip_runtime.h>
#include <hip/hip_cooperative_groups.h>
#include <math.h>

namespace cg = cooperative_groups;

#define BB 2
#define LL 8
#define HH 240
#define WW 320
#define NN (HH*WW)      // 76800
#define MM (LL*NN)      // 614400

#define DIST_TH 0.05f
#define DOT_TH  0.9396926207859084f   // cos(20 deg)
#define SIGMA   0.6f
#define EPSF    1e-8f
#define SENTINEL 0x7F7F7F7F

// ---------------------------------------------------------------------------
__device__ __forceinline__ float backproject(
    const float* __restrict__ dep,
    float fx, float fy, float cx, float cy,
    const float* __restrict__ P,
    int h, int w, float o[3])
{
    float d  = dep[h*WW + w];
    float gx = ((float)w - cx) / fx;
    float gy = ((float)h - cy) / fy;
    float px = gx*d, py = gy*d, pz = d;
    o[0] = P[0]*px + P[1]*py + P[2]*pz  + P[3];
    o[1] = P[4]*px + P[5]*py + P[6]*pz  + P[7];
    o[2] = P[8]*px + P[9]*py + P[10]*pz + P[11];
    return d;
}

__device__ __forceinline__ void frame_data(
    const float* __restrict__ rgb, const float* __restrict__ depth,
    const float* __restrict__ intr, const float* __restrict__ poses,
    int b, int s, int n,
    float fpos[3], float fn[3], float fcol[3], float& falpha, bool& fvalid)
{
    const float* Km = intr + b*16;
    float fx = Km[0], fy = Km[5], cx = Km[2], cy = Km[6];
    const float* P  = poses + (b*LL + s)*16;
    const float* dep = depth + ((size_t)(b*LL + s))*NN;

    int h = n / WW, w = n % WW;

    float p0[3], tmp[3], dx[3], dy[3];
    float d = backproject(dep, fx, fy, cx, cy, P, h, w, p0);

    if (w < WW-1) { backproject(dep, fx, fy, cx, cy, P, h, w+1, tmp);
                    dx[0]=tmp[0]-p0[0]; dx[1]=tmp[1]-p0[1]; dx[2]=tmp[2]-p0[2]; }
    else          { backproject(dep, fx, fy, cx, cy, P, h, WW-2, tmp);
                    dx[0]=p0[0]-tmp[0]; dx[1]=p0[1]-tmp[1]; dx[2]=p0[2]-tmp[2]; }

    if (h < HH-1) { backproject(dep, fx, fy, cx, cy, P, h+1, w, tmp);
                    dy[0]=tmp[0]-p0[0]; dy[1]=tmp[1]-p0[1]; dy[2]=tmp[2]-p0[2]; }
    else          { backproject(dep, fx, fy, cx, cy, P, HH-2, w, tmp);
                    dy[0]=p0[0]-tmp[0]; dy[1]=p0[1]-tmp[1]; dy[2]=p0[2]-tmp[2]; }

    float nx = dx[1]*dy[2] - dx[2]*dy[1];
    float ny = dx[2]*dy[0] - dx[0]*dy[2];
    float nz = dx[0]*dy[1] - dx[1]*dy[0];
    float nl = sqrtf(nx*nx + ny*ny + nz*nz) + EPSF;
    fn[0] = nx/nl; fn[1] = ny/nl; fn[2] = nz/nl;

    fpos[0]=p0[0]; fpos[1]=p0[1]; fpos[2]=p0[2];

    const float* c = rgb + (((size_t)(b*LL + s))*NN + n)*3;
    fcol[0]=c[0]; fcol[1]=c[1]; fcol[2]=c[2];

    float gx = ((float)w - cx)/fx, gy = ((float)h - cy)/fy;
    falpha = expf(-(gx*gx + gy*gy) / (2.0f*SIGMA*SIGMA));
    fvalid = d > 0.0f;
}

// ---------------------------------------------------------------------------
// Single cooperative kernel: init + 7 × (project, fuse) with grid syncs.
// posconf[b*MM+i] = (pos.xyz, conf) mirrors map rows for the projection read.
// ---------------------------------------------------------------------------
__global__ __launch_bounds__(256) void k_all(
    const float* __restrict__ rgb, const float* __restrict__ depth,
    const float* __restrict__ intr, const float* __restrict__ poses,
    float* __restrict__ map, float4* __restrict__ posconf,
    int* __restrict__ corr)
{
    cg::grid_group g = cg::this_grid();
    const int tid = blockIdx.x*blockDim.x + threadIdx.x;
    const int nth = gridDim.x*blockDim.x;

    // ---- Phase 0a: zero rows [NN, MM) for both batches (flat float4) ------
    {
        const int per = (MM-NN)*10/4;        // float4s per batch
        const int tot = BB*per;
        for (int k = tid; k < tot; k += nth) {
            int b = (k >= per) ? 1 : 0;
            int r = k - b*per;
            float4* dst = (float4*)(map + (size_t)b*MM*10 + (size_t)NN*10) + r;
            *dst = make_float4(0.f,0.f,0.f,0.f);
        }
    }
    // ---- Phase 0b: frame-0 rows, posconf, corr sentinel -------------------
    for (int k = tid; k < BB*NN; k += nth) {
        int b = (k >= NN) ? 1 : 0;
        int n = k - b*NN;
        float fpos[3], fn[3], fcol[3], fa; bool fv;
        frame_data(rgb, depth, intr, poses, b, 0, n, fpos, fn, fcol, fa, fv);
        float2* r2 = (float2*)(map + ((size_t)b*MM + n)*10);
        if (fv) {
            r2[0] = make_float2(fpos[0], fpos[1]);
            r2[1] = make_float2(fpos[2], fn[0]);
            r2[2] = make_float2(fn[1],  fn[2]);
            r2[3] = make_float2(fcol[0], fcol[1]);
            r2[4] = make_float2(fcol[2], fa);
            posconf[(size_t)b*MM + n] = make_float4(fpos[0], fpos[1], fpos[2], fa);
        } else {
            float2 z = make_float2(0.f,0.f);
            r2[0]=z; r2[1]=z; r2[2]=z; r2[3]=z; r2[4]=z;
            posconf[(size_t)b*MM + n] = make_float4(0.f,0.f,0.f,0.f);
        }
        corr[k] = SENTINEL;
    }
    __threadfence();
    g.sync();

    for (int s = 1; s < LL; ++s) {
        // ---- project: map points [0, s*N) -> frame s, scatter-min --------
        const int limit = s*NN;
        for (int k = tid; k < BB*limit; k += nth) {
            int b = (k >= limit) ? 1 : 0;
            int i = k - b*limit;
            float4 pc4 = posconf[(size_t)b*MM + i];
            if (!(pc4.w > 0.0f)) continue;

            const float* Km = intr + b*16;
            float fx = Km[0], fy = Km[5], cx = Km[2], cy = Km[6];
            const float* P  = poses + (b*LL + s)*16;

            float d0 = pc4.x-P[3], d1 = pc4.y-P[7], d2 = pc4.z-P[11];
            float pcx = d0*P[0] + d1*P[4] + d2*P[8];
            float pcy = d0*P[1] + d1*P[5] + d2*P[9];
            float pcz = d0*P[2] + d1*P[6] + d2*P[10];
            if (!(pcz > EPSF)) continue;

            float uf = rintf(fx*pcx/pcz + cx);
            float vf = rintf(fy*pcy/pcz + cy);
            if (!(uf >= 0.0f && uf <= (float)(WW-1) &&
                  vf >= 0.0f && vf <= (float)(HH-1))) continue;
            int ui = (int)uf, vi = (int)vf;
            atomicMin(&corr[b*NN + vi*WW + ui], i);
        }
        __threadfence();
        g.sync();

        // ---- fuse + append ----------------------------------------------
        for (int k = tid; k < BB*NN; k += nth) {
            int b = (k >= NN) ? 1 : 0;
            int n = k - b*NN;

            float fpos[3], fn[3], fcol[3], fa; bool fv;
            frame_data(rgb, depth, intr, poses, b, s, n, fpos, fn, fcol, fa, fv);

            int cv = corr[k];
            corr[k] = SENTINEL;        // owner-reset for next step

            bool match = false;
            if (cv < MM && fv) {
                int ci = cv;           // unique across threads
                float2* c2 = (float2*)(map + ((size_t)b*MM + ci)*10);
                float2 a0 = c2[0], a1 = c2[1], a2 = c2[2], a3 = c2[3], a4 = c2[4];
                float cp0=a0.x, cp1=a0.y, cp2=a1.x;
                float cn0=a1.y, cn1=a2.x, cn2=a2.y;
                float cc0=a3.x, cc1=a3.y, cc2=a4.x;
                float cw =a4.y;

                float e0 = fpos[0]-cp0, e1 = fpos[1]-cp1, e2 = fpos[2]-cp2;
                float dist = sqrtf(e0*e0 + e1*e1 + e2*e2);
                float dotp = fn[0]*cn0 + fn[1]*cn1 + fn[2]*cn2;

                if (dist < DIST_TH && dotp > DOT_TH) {
                    match = true;
                    float wgt = fa;
                    float den = cw + wgt;
                    float np0 = (cw*cp0 + wgt*fpos[0]) / den;
                    float np1 = (cw*cp1 + wgt*fpos[1]) / den;
                    float np2 = (cw*cp2 + wgt*fpos[2]) / den;
                    float nc0 = (cw*cc0 + wgt*fcol[0]) / den;
                    float nc1 = (cw*cc1 + wgt*fcol[1]) / den;
                    float nc2 = (cw*cc2 + wgt*fcol[2]) / den;
                    float nn0 = cw*cn0 + wgt*fn[0];
                    float nn1 = cw*cn1 + wgt*fn[1];
                    float nn2 = cw*cn2 + wgt*fn[2];
                    float nl  = sqrtf(nn0*nn0 + nn1*nn1 + nn2*nn2) + EPSF;
                    c2[0] = make_float2(np0, np1);
                    c2[1] = make_float2(np2, nn0/nl);
                    c2[2] = make_float2(nn1/nl, nn2/nl);
                    c2[3] = make_float2(nc0, nc1);
                    c2[4] = make_float2(nc2, den);
                    posconf[(size_t)b*MM + ci] = make_float4(np0, np1, np2, den);
                }
            }

            size_t slot = (size_t)b*MM + (size_t)s*NN + n;
            float2* s2 = (float2*)(map + slot*10);
            bool app = fv && !match;
            if (app) {
                s2[0] = make_float2(fpos[0], fpos[1]);
                s2[1] = make_float2(fpos[2], fn[0]);
                s2[2] = make_float2(fn[1],  fn[2]);
                s2[3] = make_float2(fcol[0], fcol[1]);
                s2[4] = make_float2(fcol[2], fa);
                posconf[slot] = make_float4(fpos[0], fpos[1], fpos[2], fa);
            } else {
                float2 z = make_float2(0.f,0.f);
                s2[0]=z; s2[1]=z; s2[2]=z; s2[3]=z; s2[4]=z;
                posconf[slot] = make_float4(0.f,0.f,0.f,0.f);
            }
        }
        __threadfence();
        g.sync();
    }
}

// ---------------------------------------------------------------------------
extern "C" void kernel_launch(void* const* d_in, const int* in_sizes, int n_in,
                              void* d_out, int out_size, void* d_ws, size_t ws_size,
                              hipStream_t stream) {
    const float* rgb   = (const float*)d_in[0];  // (B,L,H,W,3)
    const float* depth = (const float*)d_in[1];  // (B,L,H,W,1)
    const float* intr  = (const float*)d_in[2];  // (B,1,4,4)
    const float* poses = (const float*)d_in[3];  // (B,L,4,4)
    float* map = (float*)d_out;                  // (B,M,10)

    float4* posconf = (float4*)d_ws;                               // B*M float4 (~19.7 MB)
    int*    corr    = (int*)((char*)d_ws + (size_t)BB*MM*sizeof(float4)); // B*N ints

    int maxb = 0;
    hipError_t e = hipOccupancyMaxActiveBlocksPerMultiprocessor(&maxb, k_all, 256, 0);
    int grid = (e == hipSuccess && maxb > 0) ? maxb * 256 /*CUs*/ : 512;
    if (grid > 1024) grid = 1024;   // bound grid-sync cost; grid-stride covers the rest
    if (grid < 256)  grid = 256;

    void* args[] = { (void*)&rgb, (void*)&depth, (void*)&intr, (void*)&poses,
                     (void*)&map, (void*)&posconf, (void*)&corr };
    hipLaunchCooperativeKernel((void*)k_all, dim3(grid), dim3(256), args, 0, stream);
}

// Round 3
// 177.695 us; speedup vs baseline: 14.5952x; 14.5952x over previous
//
#include <hip/hip_runtime.h>
#include <math.h>

#define BB 2
#define LL 8
#define HH 240
#define WW 320
#define NN (HH*WW)      // 76800
#define MM (LL*NN)      // 614400

#define DIST_TH 0.05f
#define DOT_TH  0.9396926207859084f   // cos(20 deg)
#define SIGMA   0.6f
#define EPSF    1e-8f
#define SENTINEL 0x7F7F7F7F

// ---------------------------------------------------------------------------
__device__ __forceinline__ float backproject(
    const float* __restrict__ dep,
    float fx, float fy, float cx, float cy,
    const float* __restrict__ P,
    int h, int w, float o[3])
{
    float d  = dep[h*WW + w];
    float gx = ((float)w - cx) / fx;
    float gy = ((float)h - cy) / fy;
    float px = gx*d, py = gy*d, pz = d;
    o[0] = P[0]*px + P[1]*py + P[2]*pz  + P[3];
    o[1] = P[4]*px + P[5]*py + P[6]*pz  + P[7];
    o[2] = P[8]*px + P[9]*py + P[10]*pz + P[11];
    return d;
}

__device__ __forceinline__ void frame_data(
    const float* __restrict__ rgb, const float* __restrict__ depth,
    const float* __restrict__ intr, const float* __restrict__ poses,
    int b, int s, int n,
    float fpos[3], float fn[3], float fcol[3], float& falpha, bool& fvalid)
{
    const float* Km = intr + b*16;
    float fx = Km[0], fy = Km[5], cx = Km[2], cy = Km[6];
    const float* P  = poses + (b*LL + s)*16;
    const float* dep = depth + ((size_t)(b*LL + s))*NN;

    int h = n / WW, w = n % WW;

    float p0[3], tmp[3], dx[3], dy[3];
    float d = backproject(dep, fx, fy, cx, cy, P, h, w, p0);

    if (w < WW-1) { backproject(dep, fx, fy, cx, cy, P, h, w+1, tmp);
                    dx[0]=tmp[0]-p0[0]; dx[1]=tmp[1]-p0[1]; dx[2]=tmp[2]-p0[2]; }
    else          { backproject(dep, fx, fy, cx, cy, P, h, WW-2, tmp);
                    dx[0]=p0[0]-tmp[0]; dx[1]=p0[1]-tmp[1]; dx[2]=p0[2]-tmp[2]; }

    if (h < HH-1) { backproject(dep, fx, fy, cx, cy, P, h+1, w, tmp);
                    dy[0]=tmp[0]-p0[0]; dy[1]=tmp[1]-p0[1]; dy[2]=tmp[2]-p0[2]; }
    else          { backproject(dep, fx, fy, cx, cy, P, HH-2, w, tmp);
                    dy[0]=p0[0]-tmp[0]; dy[1]=p0[1]-tmp[1]; dy[2]=p0[2]-tmp[2]; }

    float nx = dx[1]*dy[2] - dx[2]*dy[1];
    float ny = dx[2]*dy[0] - dx[0]*dy[2];
    float nz = dx[0]*dy[1] - dx[1]*dy[0];
    float nl = sqrtf(nx*nx + ny*ny + nz*nz) + EPSF;
    fn[0] = nx/nl; fn[1] = ny/nl; fn[2] = nz/nl;

    fpos[0]=p0[0]; fpos[1]=p0[1]; fpos[2]=p0[2];

    const float* c = rgb + (((size_t)(b*LL + s))*NN + n)*3;
    fcol[0]=c[0]; fcol[1]=c[1]; fcol[2]=c[2];

    float gx = ((float)w - cx)/fx, gy = ((float)h - cy)/fy;
    falpha = expf(-(gx*gx + gy*gy) / (2.0f*SIGMA*SIGMA));
    fvalid = d > 0.0f;
}

// ---------------------------------------------------------------------------
// Kernel 1: full init. Zero rows [N,M) (flat float4), frame-0 rows + posconf
// mirror for [0,N), corr sentinel. One dispatch, write-bound (~70 MB).
// ---------------------------------------------------------------------------
__global__ __launch_bounds__(256) void k_init(
    const float* __restrict__ rgb, const float* __restrict__ depth,
    const float* __restrict__ intr, const float* __restrict__ poses,
    float* __restrict__ map, float4* __restrict__ posconf,
    int* __restrict__ corr)
{
    const int b   = blockIdx.y;
    const int tid = blockIdx.x*blockDim.x + threadIdx.x;
    const int nth = gridDim.x*blockDim.x;

    // zero map rows [NN, MM): (MM-NN)*10/4 float4s, 16B-aligned
    {
        float4* dst = (float4*)(map + (size_t)b*MM*10 + (size_t)NN*10);
        const int Z = (MM-NN)*10/4;   // 1,344,000
        for (int r = tid; r < Z; r += nth)
            dst[r] = make_float4(0.f,0.f,0.f,0.f);
    }

    // frame-0 rows + posconf + corr
    for (int n = tid; n < NN; n += nth) {
        float fpos[3], fn[3], fcol[3], fa; bool fv;
        frame_data(rgb, depth, intr, poses, b, 0, n, fpos, fn, fcol, fa, fv);
        float2* r2 = (float2*)(map + ((size_t)b*MM + n)*10);
        if (fv) {
            r2[0] = make_float2(fpos[0], fpos[1]);
            r2[1] = make_float2(fpos[2], fn[0]);
            r2[2] = make_float2(fn[1],  fn[2]);
            r2[3] = make_float2(fcol[0], fcol[1]);
            r2[4] = make_float2(fcol[2], fa);
            posconf[(size_t)b*MM + n] = make_float4(fpos[0], fpos[1], fpos[2], fa);
        } else {
            float2 z = make_float2(0.f,0.f);
            r2[0]=z; r2[1]=z; r2[2]=z; r2[3]=z; r2[4]=z;
            posconf[(size_t)b*MM + n] = make_float4(0.f,0.f,0.f,0.f);
        }
        corr[b*NN + n] = SENTINEL;
    }
}

// ---------------------------------------------------------------------------
// Kernel 2 (per step s): project map points [0, s*N) via compact posconf,
// scatter-min winning map index per pixel.
// ---------------------------------------------------------------------------
__global__ __launch_bounds__(256) void k_project(
    const float* __restrict__ intr, const float* __restrict__ poses,
    const float4* __restrict__ posconf, int* __restrict__ corr, int s)
{
    int b = blockIdx.y;
    int i = blockIdx.x*blockDim.x + threadIdx.x;
    if (i >= s*NN) return;

    float4 pc4 = posconf[(size_t)b*MM + i];
    if (!(pc4.w > 0.0f)) return;

    const float* Km = intr + b*16;
    float fx = Km[0], fy = Km[5], cx = Km[2], cy = Km[6];
    const float* P  = poses + (b*LL + s)*16;

    float d0 = pc4.x-P[3], d1 = pc4.y-P[7], d2 = pc4.z-P[11];
    float pcx = d0*P[0] + d1*P[4] + d2*P[8];
    float pcy = d0*P[1] + d1*P[5] + d2*P[9];
    float pcz = d0*P[2] + d1*P[6] + d2*P[10];
    if (!(pcz > EPSF)) return;

    float uf = rintf(fx*pcx/pcz + cx);   // half-to-even, matches jnp.round
    float vf = rintf(fy*pcy/pcz + cy);
    if (!(uf >= 0.0f && uf <= (float)(WW-1) &&
          vf >= 0.0f && vf <= (float)(HH-1))) return;
    int ui = (int)uf, vi = (int)vf;
    atomicMin(&corr[b*NN + vi*WW + ui], i);
}

// ---------------------------------------------------------------------------
// Kernel 3 (per step s): fuse matched rows + append frame features.
// Non-appended slot rows stay zero from k_init (no redundant store);
// posconf mirror is always written for slot rows. Thread-owned corr reset.
// ---------------------------------------------------------------------------
__global__ __launch_bounds__(256) void k_fuse(
    const float* __restrict__ rgb, const float* __restrict__ depth,
    const float* __restrict__ intr, const float* __restrict__ poses,
    float* __restrict__ map, float4* __restrict__ posconf,
    int* __restrict__ corr, int s)
{
    int b = blockIdx.y;
    int n = blockIdx.x*blockDim.x + threadIdx.x;
    if (n >= NN) return;

    float fpos[3], fn[3], fcol[3], fa; bool fv;
    frame_data(rgb, depth, intr, poses, b, s, n, fpos, fn, fcol, fa, fv);

    int cv = corr[b*NN + n];
    corr[b*NN + n] = SENTINEL;   // owner-reset for next step

    bool match = false;
    if (cv < MM && fv) {
        int ci = cv;             // unique across threads (one winner per pixel)
        float2* c2 = (float2*)(map + ((size_t)b*MM + ci)*10);
        float2 a0 = c2[0], a1 = c2[1], a2 = c2[2], a3 = c2[3], a4 = c2[4];
        float cp0=a0.x, cp1=a0.y, cp2=a1.x;
        float cn0=a1.y, cn1=a2.x, cn2=a2.y;
        float cc0=a3.x, cc1=a3.y, cc2=a4.x;
        float cw =a4.y;

        float e0 = fpos[0]-cp0, e1 = fpos[1]-cp1, e2 = fpos[2]-cp2;
        float dist = sqrtf(e0*e0 + e1*e1 + e2*e2);
        float dotp = fn[0]*cn0 + fn[1]*cn1 + fn[2]*cn2;

        if (dist < DIST_TH && dotp > DOT_TH) {
            match = true;
            float wgt = fa;
            float den = cw + wgt;
            float np0 = (cw*cp0 + wgt*fpos[0]) / den;
            float np1 = (cw*cp1 + wgt*fpos[1]) / den;
            float np2 = (cw*cp2 + wgt*fpos[2]) / den;
            float nc0 = (cw*cc0 + wgt*fcol[0]) / den;
            float nc1 = (cw*cc1 + wgt*fcol[1]) / den;
            float nc2 = (cw*cc2 + wgt*fcol[2]) / den;
            float nn0 = cw*cn0 + wgt*fn[0];
            float nn1 = cw*cn1 + wgt*fn[1];
            float nn2 = cw*cn2 + wgt*fn[2];
            float nl  = sqrtf(nn0*nn0 + nn1*nn1 + nn2*nn2) + EPSF;
            c2[0] = make_float2(np0, np1);
            c2[1] = make_float2(np2, nn0/nl);
            c2[2] = make_float2(nn1/nl, nn2/nl);
            c2[3] = make_float2(nc0, nc1);
            c2[4] = make_float2(nc2, den);
            posconf[(size_t)b*MM + ci] = make_float4(np0, np1, np2, den);
        }
    }

    size_t slot = (size_t)b*MM + (size_t)s*NN + n;
    bool app = fv && !match;
    if (app) {
        float2* s2 = (float2*)(map + slot*10);
        s2[0] = make_float2(fpos[0], fpos[1]);
        s2[1] = make_float2(fpos[2], fn[0]);
        s2[2] = make_float2(fn[1],  fn[2]);
        s2[3] = make_float2(fcol[0], fcol[1]);
        s2[4] = make_float2(fcol[2], fa);
        posconf[slot] = make_float4(fpos[0], fpos[1], fpos[2], fa);
    } else {
        // map row already zero from k_init; only the mirror needs the zero
        posconf[slot] = make_float4(0.f,0.f,0.f,0.f);
    }
}

// ---------------------------------------------------------------------------
extern "C" void kernel_launch(void* const* d_in, const int* in_sizes, int n_in,
                              void* d_out, int out_size, void* d_ws, size_t ws_size,
                              hipStream_t stream) {
    const float* rgb   = (const float*)d_in[0];  // (B,L,H,W,3)
    const float* depth = (const float*)d_in[1];  // (B,L,H,W,1)
    const float* intr  = (const float*)d_in[2];  // (B,1,4,4)
    const float* poses = (const float*)d_in[3];  // (B,L,4,4)
    float* map = (float*)d_out;                  // (B,M,10)

    float4* posconf = (float4*)d_ws;                                      // B*M float4
    int*    corr    = (int*)((char*)d_ws + (size_t)BB*MM*sizeof(float4)); // B*N ints

    dim3 blk(256);
    // 1344 blocks: zero-loop ~4 iters, frame0-loop 1 iter per b
    k_init<<<dim3(1344, BB), blk, 0, stream>>>(rgb, depth, intr, poses,
                                               map, posconf, corr);

    for (int s = 1; s < LL; ++s) {
        int limit = s*NN;
        k_project<<<dim3((limit+255)/256, BB), blk, 0, stream>>>(
            intr, poses, posconf, corr, s);
        k_fuse<<<dim3((NN+255)/256, BB), blk, 0, stream>>>(
            rgb, depth, intr, poses, map, posconf, corr, s);
    }
}

// Round 4
// 175.722 us; speedup vs baseline: 14.7590x; 1.0112x over previous
//
#include <hip/hip_runtime.h>
#include <math.h>

#define BB 2
#define LL 8
#define HH 240
#define WW 320
#define NN (HH*WW)      // 76800
#define MM (LL*NN)      // 614400

#define DIST_TH 0.05f
#define DOT_TH  0.9396926207859084f   // cos(20 deg)
#define SIGMA   0.6f
#define EPSF    1e-8f
#define SENTINEL 0x7F7F7F7F

// ---------------------------------------------------------------------------
__device__ __forceinline__ float backproject(
    const float* __restrict__ dep,
    float fx, float fy, float cx, float cy,
    const float* __restrict__ P,
    int h, int w, float o[3])
{
    float d  = dep[h*WW + w];
    float gx = ((float)w - cx) / fx;
    float gy = ((float)h - cy) / fy;
    float px = gx*d, py = gy*d, pz = d;
    o[0] = P[0]*px + P[1]*py + P[2]*pz  + P[3];
    o[1] = P[4]*px + P[5]*py + P[6]*pz  + P[7];
    o[2] = P[8]*px + P[9]*py + P[10]*pz + P[11];
    return d;
}

__device__ __forceinline__ void frame_data(
    const float* __restrict__ rgb, const float* __restrict__ depth,
    const float* __restrict__ intr, const float* __restrict__ poses,
    int b, int s, int n,
    float fpos[3], float fn[3], float fcol[3], float& falpha, bool& fvalid)
{
    const float* Km = intr + b*16;
    float fx = Km[0], fy = Km[5], cx = Km[2], cy = Km[6];
    const float* P  = poses + (b*LL + s)*16;
    const float* dep = depth + ((size_t)(b*LL + s))*NN;

    int h = n / WW, w = n % WW;

    float p0[3], tmp[3], dx[3], dy[3];
    float d = backproject(dep, fx, fy, cx, cy, P, h, w, p0);

    if (w < WW-1) { backproject(dep, fx, fy, cx, cy, P, h, w+1, tmp);
                    dx[0]=tmp[0]-p0[0]; dx[1]=tmp[1]-p0[1]; dx[2]=tmp[2]-p0[2]; }
    else          { backproject(dep, fx, fy, cx, cy, P, h, WW-2, tmp);
                    dx[0]=p0[0]-tmp[0]; dx[1]=p0[1]-tmp[1]; dx[2]=p0[2]-tmp[2]; }

    if (h < HH-1) { backproject(dep, fx, fy, cx, cy, P, h+1, w, tmp);
                    dy[0]=tmp[0]-p0[0]; dy[1]=tmp[1]-p0[1]; dy[2]=tmp[2]-p0[2]; }
    else          { backproject(dep, fx, fy, cx, cy, P, HH-2, w, tmp);
                    dy[0]=p0[0]-tmp[0]; dy[1]=p0[1]-tmp[1]; dy[2]=p0[2]-tmp[2]; }

    float nx = dx[1]*dy[2] - dx[2]*dy[1];
    float ny = dx[2]*dy[0] - dx[0]*dy[2];
    float nz = dx[0]*dy[1] - dx[1]*dy[0];
    float nl = sqrtf(nx*nx + ny*ny + nz*nz) + EPSF;
    fn[0] = nx/nl; fn[1] = ny/nl; fn[2] = nz/nl;

    fpos[0]=p0[0]; fpos[1]=p0[1]; fpos[2]=p0[2];

    const float* c = rgb + (((size_t)(b*LL + s))*NN + n)*3;
    fcol[0]=c[0]; fcol[1]=c[1]; fcol[2]=c[2];

    float gx = ((float)w - cx)/fx, gy = ((float)h - cy)/fy;
    falpha = expf(-(gx*gx + gy*gy) / (2.0f*SIGMA*SIGMA));
    fvalid = d > 0.0f;
}

// ---------------------------------------------------------------------------
// Kernel 1: init. Frame-0 rows + posconf mirror + corr sentinel ONLY.
// Rows [N,M) are written (data or zeros) by their step's k_fuse, so no
// bulk zero-fill here — saves ~43 MB of writes per call.
// ---------------------------------------------------------------------------
__global__ __launch_bounds__(256) void k_init(
    const float* __restrict__ rgb, const float* __restrict__ depth,
    const float* __restrict__ intr, const float* __restrict__ poses,
    float* __restrict__ map, float4* __restrict__ posconf,
    int* __restrict__ corr)
{
    const int b = blockIdx.y;
    const int n = blockIdx.x*blockDim.x + threadIdx.x;
    if (n >= NN) return;

    float fpos[3], fn[3], fcol[3], fa; bool fv;
    frame_data(rgb, depth, intr, poses, b, 0, n, fpos, fn, fcol, fa, fv);
    float2* r2 = (float2*)(map + ((size_t)b*MM + n)*10);
    if (fv) {
        r2[0] = make_float2(fpos[0], fpos[1]);
        r2[1] = make_float2(fpos[2], fn[0]);
        r2[2] = make_float2(fn[1],  fn[2]);
        r2[3] = make_float2(fcol[0], fcol[1]);
        r2[4] = make_float2(fcol[2], fa);
        posconf[(size_t)b*MM + n] = make_float4(fpos[0], fpos[1], fpos[2], fa);
    } else {
        float2 z = make_float2(0.f,0.f);
        r2[0]=z; r2[1]=z; r2[2]=z; r2[3]=z; r2[4]=z;
        posconf[(size_t)b*MM + n] = make_float4(0.f,0.f,0.f,0.f);
    }
    corr[b*NN + n] = SENTINEL;
}

// ---------------------------------------------------------------------------
// Kernel 2 (per step s): project map points [0, s*N) via compact posconf,
// scatter-min winning map index per pixel.
// ---------------------------------------------------------------------------
__global__ __launch_bounds__(256) void k_project(
    const float* __restrict__ intr, const float* __restrict__ poses,
    const float4* __restrict__ posconf, int* __restrict__ corr, int s)
{
    int b = blockIdx.y;
    int i = blockIdx.x*blockDim.x + threadIdx.x;
    if (i >= s*NN) return;

    float4 pc4 = posconf[(size_t)b*MM + i];
    if (!(pc4.w > 0.0f)) return;

    const float* Km = intr + b*16;
    float fx = Km[0], fy = Km[5], cx = Km[2], cy = Km[6];
    const float* P  = poses + (b*LL + s)*16;

    float d0 = pc4.x-P[3], d1 = pc4.y-P[7], d2 = pc4.z-P[11];
    float pcx = d0*P[0] + d1*P[4] + d2*P[8];
    float pcy = d0*P[1] + d1*P[5] + d2*P[9];
    float pcz = d0*P[2] + d1*P[6] + d2*P[10];
    if (!(pcz > EPSF)) return;

    float uf = rintf(fx*pcx/pcz + cx);   // half-to-even, matches jnp.round
    float vf = rintf(fy*pcy/pcz + cy);
    if (!(uf >= 0.0f && uf <= (float)(WW-1) &&
          vf >= 0.0f && vf <= (float)(HH-1))) return;
    int ui = (int)uf, vi = (int)vf;
    atomicMin(&corr[b*NN + vi*WW + ui], i);
}

// ---------------------------------------------------------------------------
// Kernel 3 (per step s): fuse matched rows + append frame features.
// Slot row [s*N + n] is ALWAYS written here (data or zeros) — exactly once
// per call. Thread-owned corr reset for the next step.
// ---------------------------------------------------------------------------
__global__ __launch_bounds__(256) void k_fuse(
    const float* __restrict__ rgb, const float* __restrict__ depth,
    const float* __restrict__ intr, const float* __restrict__ poses,
    float* __restrict__ map, float4* __restrict__ posconf,
    int* __restrict__ corr, int s)
{
    int b = blockIdx.y;
    int n = blockIdx.x*blockDim.x + threadIdx.x;
    if (n >= NN) return;

    float fpos[3], fn[3], fcol[3], fa; bool fv;
    frame_data(rgb, depth, intr, poses, b, s, n, fpos, fn, fcol, fa, fv);

    int cv = corr[b*NN + n];
    corr[b*NN + n] = SENTINEL;   // owner-reset for next step

    bool match = false;
    if (cv < MM && fv) {
        int ci = cv;             // unique across threads (one winner per pixel)
        float2* c2 = (float2*)(map + ((size_t)b*MM + ci)*10);
        float2 a0 = c2[0], a1 = c2[1], a2 = c2[2], a3 = c2[3], a4 = c2[4];
        float cp0=a0.x, cp1=a0.y, cp2=a1.x;
        float cn0=a1.y, cn1=a2.x, cn2=a2.y;
        float cc0=a3.x, cc1=a3.y, cc2=a4.x;
        float cw =a4.y;

        float e0 = fpos[0]-cp0, e1 = fpos[1]-cp1, e2 = fpos[2]-cp2;
        float dist = sqrtf(e0*e0 + e1*e1 + e2*e2);
        float dotp = fn[0]*cn0 + fn[1]*cn1 + fn[2]*cn2;

        if (dist < DIST_TH && dotp > DOT_TH) {
            match = true;
            float wgt = fa;
            float den = cw + wgt;
            float np0 = (cw*cp0 + wgt*fpos[0]) / den;
            float np1 = (cw*cp1 + wgt*fpos[1]) / den;
            float np2 = (cw*cp2 + wgt*fpos[2]) / den;
            float nc0 = (cw*cc0 + wgt*fcol[0]) / den;
            float nc1 = (cw*cc1 + wgt*fcol[1]) / den;
            float nc2 = (cw*cc2 + wgt*fcol[2]) / den;
            float nn0 = cw*cn0 + wgt*fn[0];
            float nn1 = cw*cn1 + wgt*fn[1];
            float nn2 = cw*cn2 + wgt*fn[2];
            float nl  = sqrtf(nn0*nn0 + nn1*nn1 + nn2*nn2) + EPSF;
            c2[0] = make_float2(np0, np1);
            c2[1] = make_float2(np2, nn0/nl);
            c2[2] = make_float2(nn1/nl, nn2/nl);
            c2[3] = make_float2(nc0, nc1);
            c2[4] = make_float2(nc2, den);
            posconf[(size_t)b*MM + ci] = make_float4(np0, np1, np2, den);
        }
    }

    size_t slot = (size_t)b*MM + (size_t)s*NN + n;
    float2* s2 = (float2*)(map + slot*10);
    bool app = fv && !match;
    if (app) {
        s2[0] = make_float2(fpos[0], fpos[1]);
        s2[1] = make_float2(fpos[2], fn[0]);
        s2[2] = make_float2(fn[1],  fn[2]);
        s2[3] = make_float2(fcol[0], fcol[1]);
        s2[4] = make_float2(fcol[2], fa);
        posconf[slot] = make_float4(fpos[0], fpos[1], fpos[2], fa);
    } else {
        float2 z = make_float2(0.f,0.f);
        s2[0]=z; s2[1]=z; s2[2]=z; s2[3]=z; s2[4]=z;
        posconf[slot] = make_float4(0.f,0.f,0.f,0.f);
    }
}

// ---------------------------------------------------------------------------
extern "C" void kernel_launch(void* const* d_in, const int* in_sizes, int n_in,
                              void* d_out, int out_size, void* d_ws, size_t ws_size,
                              hipStream_t stream) {
    const float* rgb   = (const float*)d_in[0];  // (B,L,H,W,3)
    const float* depth = (const float*)d_in[1];  // (B,L,H,W,1)
    const float* intr  = (const float*)d_in[2];  // (B,1,4,4)
    const float* poses = (const float*)d_in[3];  // (B,L,4,4)
    float* map = (float*)d_out;                  // (B,M,10)

    float4* posconf = (float4*)d_ws;                                      // B*M float4
    int*    corr    = (int*)((char*)d_ws + (size_t)BB*MM*sizeof(float4)); // B*N ints

    dim3 blk(256);
    k_init<<<dim3((NN+255)/256, BB), blk, 0, stream>>>(rgb, depth, intr, poses,
                                                       map, posconf, corr);

    for (int s = 1; s < LL; ++s) {
        int limit = s*NN;
        k_project<<<dim3((limit+255)/256, BB), blk, 0, stream>>>(
            intr, poses, posconf, corr, s);
        k_fuse<<<dim3((NN+255)/256, BB), blk, 0, stream>>>(
            rgb, depth, intr, poses, map, posconf, corr, s);
    }
}